// Round 10
// baseline (487.454 us; speedup 1.0000x reference)
//
#include <hip/hip_runtime.h>
#include <math.h>

#define B_ 8192
#define D_ 4096
#define K_ 64
#define EPSF 1e-8f
#define LN2F 0.69314718056f
#define ENT_GRID 2048
#define TILES 16   // column tiles of 256 floats
#define RSPLIT 16  // row splits of 512 sequential rows

typedef float f32x4 __attribute__((ext_vector_type(4)));

// ---------------- kernels ----------------

// one wave per row; K_ == 64 == wavefront: one coalesced read + ballot
__global__ void k_labels(const float* __restrict__ probs, int* __restrict__ labels) {
  int row = blockIdx.x * 4 + (threadIdx.x >> 6);
  int lane = threadIdx.x & 63;
  float p = probs[(size_t)row * K_ + lane];
  unsigned long long m = __ballot(p > 0.5f);
  if (lane == 0) {
    int k = __ffsll(m) - 1;
    labels[row] = (k >= 0) ? k : 0;
  }
}

// block per row, sequential rows: w = 1/max(||a||,eps), diag = s*w*w.
// Plain stores only (proven ~6.4 TB/s shape).
__global__ __launch_bounds__(256) void k_norms(const float* __restrict__ acts,
                                               float* __restrict__ wout,
                                               float* __restrict__ diagout) {
  __shared__ float lds[4];
  int row = blockIdx.x;
  const f32x4* rp = (const f32x4*)(acts + (size_t)row * D_);
  int t = threadIdx.x;
  f32x4 v0 = rp[t];
  f32x4 v1 = rp[t + 256];
  f32x4 v2 = rp[t + 512];
  f32x4 v3 = rp[t + 768];
  float s = v0.x * v0.x + v0.y * v0.y + v0.z * v0.z + v0.w * v0.w;
  s += v1.x * v1.x + v1.y * v1.y + v1.z * v1.z + v1.w * v1.w;
  s += v2.x * v2.x + v2.y * v2.y + v2.z * v2.z + v2.w * v2.w;
  s += v3.x * v3.x + v3.y * v3.y + v3.z * v3.z + v3.w * v3.w;
#pragma unroll
  for (int o = 32; o > 0; o >>= 1) s += __shfl_down(s, o);
  if ((t & 63) == 0) lds[t >> 6] = s;
  __syncthreads();
  if (t == 0) {
    s = lds[0] + lds[1] + lds[2] + lds[3];
    float w = 1.0f / fmaxf(sqrtf(s), EPSF);
    wout[row] = w;
    diagout[row] = s * w * w;
  }
}

// Streaming class-sum scatter: block = (col-tile 256, row-split 512 SEQUENTIAL rows).
// Thread tid owns LDS column tid: C[k][tid] touched by no other thread ->
// atomicAdd is contention-free ds_add_f32 (fire-and-forget, no RMW chain).
// Reads are fully coalesced (block reads 1KB contiguous per row) and L3-hot
// (runs right after k_norms streamed this tensor).
__global__ __launch_bounds__(256) void k_scatter(const float* __restrict__ acts,
                                                 const int* __restrict__ labels,
                                                 const float* __restrict__ warr,
                                                 float* __restrict__ Cpart) {
  __shared__ float C[K_][256];
  int tile = blockIdx.x & (TILES - 1);
  int split = blockIdx.x / TILES;
  int tid = threadIdx.x;
  // zero own column (no barrier needed anywhere: column is thread-private)
  float* Cf = &C[0][0];
#pragma unroll
  for (int j = 0; j < K_; ++j) Cf[j * 256 + tid] = 0.f;

  const int ROWS = B_ / RSPLIT;  // 512
  int rbase = split * ROWS;
  const float* ap = acts + (size_t)rbase * D_ + tile * 256 + tid;
  const int* lp = labels + rbase;
  const float* wp = warr + rbase;

  for (int it = 0; it < ROWS; it += 16) {
    float v[16], wv[16];
    int lb[16];
    const float* api = ap + (size_t)it * D_;
#pragma unroll
    for (int j = 0; j < 16; ++j) v[j] = api[(size_t)j * D_];
#pragma unroll
    for (int j = 0; j < 16; ++j) {
      lb[j] = lp[it + j];
      wv[j] = wp[it + j];
    }
#pragma unroll
    for (int j = 0; j < 16; ++j) atomicAdd(&C[lb[j]][tid], wv[j] * v[j]);
  }

  // writeback own column: Cpart[split][k][tile*256+tid]
  float* cp = Cpart + (size_t)split * K_ * D_ + tile * 256 + tid;
#pragma unroll
  for (int k = 0; k < K_; ++k) cp[(size_t)k * D_] = C[k][tid];
}

// mSm partials: 512 blocks; b<256 -> tensor1, else tensor8. k=b>>2, quarter q=b&3.
__global__ __launch_bounds__(256) void k_msm(const float* __restrict__ Cpart1,
                                             const float* __restrict__ Cpart8,
                                             float* __restrict__ msp1,
                                             float* __restrict__ msp8) {
  __shared__ float lds[4];
  int b = blockIdx.x;
  const float* Cpart = (b < 256) ? Cpart1 : Cpart8;
  float* msp = (b < 256) ? msp1 : msp8;
  b &= 255;
  int k = b >> 2;
  int q = b & 3;
  int t = threadIdx.x;
  int col = q * 1024 + 4 * t;
  f32x4 c = 0.f;
#pragma unroll
  for (int s = 0; s < RSPLIT; ++s)
    c += *(const f32x4*)(Cpart + ((size_t)s * K_ + k) * D_ + col);
  float sq = c.x * c.x + c.y * c.y + c.z * c.z + c.w * c.w;
#pragma unroll
  for (int o = 32; o > 0; o >>= 1) sq += __shfl_down(sq, o);
  if ((t & 63) == 0) lds[t >> 6] = sq;
  __syncthreads();
  if (t == 0) msp[blockIdx.x & 255] = lds[0] + lds[1] + lds[2] + lds[3];
}

__device__ __forceinline__ float ent1(float p) {
  p = fminf(fmaxf(p, EPSF), 1.0f - EPSF);
  float q = 1.0f - p;
  float lp = __builtin_amdgcn_logf(p);  // v_log_f32: log2
  float lq = __builtin_amdgcn_logf(fmaxf(q, 1e-38f));
  return -(p * lp + q * lq);
}

__device__ __forceinline__ float ent4(f32x4 v) {
  return ent1(v.x) + ent1(v.y) + ent1(v.z) + ent1(v.w);
}

// binary entropy over both masks; plain loads, 16 in flight (r8-proven shape)
__global__ __launch_bounds__(256) void k_entropy(const f32x4* __restrict__ m1,
                                                 const f32x4* __restrict__ m8,
                                                 double* __restrict__ entpart) {
  __shared__ float lds[8];
  const int CHUNK = (B_ * D_ / 4) / ENT_GRID;  // 4096 f32x4 per block per mask
  int base = blockIdx.x * CHUNK;
  int t = threadIdx.x;
  float s1 = 0.f, s8 = 0.f;
#pragma unroll
  for (int o = 0; o < 2; ++o) {
    f32x4 a[8], b[8];
#pragma unroll
    for (int j = 0; j < 8; ++j) {
      int idx = base + t + (o * 8 + j) * 256;
      a[j] = m1[idx];
      b[j] = m8[idx];
    }
#pragma unroll
    for (int j = 0; j < 8; ++j) {
      s1 += ent4(a[j]);
      s8 += ent4(b[j]);
    }
  }
#pragma unroll
  for (int o = 32; o > 0; o >>= 1) {
    s1 += __shfl_down(s1, o);
    s8 += __shfl_down(s8, o);
  }
  int wid = t >> 6;
  if ((t & 63) == 0) { lds[wid] = s1; lds[4 + wid] = s8; }
  __syncthreads();
  if (t == 0) {
    float t1 = lds[0] + lds[1] + lds[2] + lds[3];
    float t8 = lds[4] + lds[5] + lds[6] + lds[7];
    entpart[blockIdx.x]            = (double)(t1 * LN2F);
    entpart[ENT_GRID + blockIdx.x] = (double)(t8 * LN2F);
  }
}

__global__ void k_final(const double* __restrict__ entpart, const int* __restrict__ labels,
                        const float* __restrict__ diag1, const float* __restrict__ diag8,
                        const float* __restrict__ msp1, const float* __restrict__ msp8,
                        float* __restrict__ out) {
  __shared__ float sd1[K_], sd8[K_];
  __shared__ int cnt[K_];
  __shared__ double dl[8];
  int t = threadIdx.x;
  if (t < K_) { sd1[t] = 0.f; sd8[t] = 0.f; cnt[t] = 0; }
  __syncthreads();
  for (int r = t; r < B_; r += 256) {
    int lb = labels[r];
    atomicAdd(&sd1[lb], diag1[r]);
    atomicAdd(&sd8[lb], diag8[r]);
    atomicAdd(&cnt[lb], 1);
  }
  double e1 = 0.0, e8 = 0.0;
  for (int i = t; i < ENT_GRID; i += 256) {
    e1 += entpart[i];
    e8 += entpart[ENT_GRID + i];
  }
#pragma unroll
  for (int o = 32; o > 0; o >>= 1) {
    e1 += __shfl_down(e1, o);
    e8 += __shfl_down(e8, o);
  }
  int wid = t >> 6;
  if ((t & 63) == 0) { dl[wid] = e1; dl[4 + wid] = e8; }
  __syncthreads();  // covers sd/cnt atomics and dl stores
  float pcm1 = 0.f, pcm8 = 0.f, valid = 0.f;
  if (t < K_) {
    float mSm1 = msp1[t * 4] + msp1[t * 4 + 1] + msp1[t * 4 + 2] + msp1[t * 4 + 3];
    float mSm8 = msp8[t * 4] + msp8[t * 4 + 1] + msp8[t * 4 + 2] + msp8[t * 4 + 3];
    float n = (float)cnt[t];
    bool v = (n >= 2.0f);
    float np = fmaxf(0.5f * n * (n - 1.0f), 1.0f);
    valid = v ? 1.0f : 0.f;
    pcm1 = v ? 0.5f * (mSm1 - sd1[t]) / np : 0.f;
    pcm8 = v ? 0.5f * (mSm8 - sd8[t]) / np : 0.f;
  }
#pragma unroll
  for (int o = 32; o > 0; o >>= 1) {
    pcm1 += __shfl_down(pcm1, o);
    pcm8 += __shfl_down(pcm8, o);
    valid += __shfl_down(valid, o);
  }
  if (t == 0) {
    double etot1 = dl[0] + dl[1] + dl[2] + dl[3];
    double etot8 = dl[4] + dl[5] + dl[6] + dl[7];
    float sp1 = (float)(etot1 / (double)((long long)B_ * D_));
    float sp8 = (float)(etot8 / (double)((long long)B_ * D_));
    float cs1 = (valid > 0.f) ? pcm1 / fmaxf(valid, 1.0f) : 0.f;
    float cs8 = (valid > 0.f) ? pcm8 / fmaxf(valid, 1.0f) : 0.f;
    float sim1 = -cs1, sim8 = -cs8;
    out[0] = sim1 + sim8 + 0.001f * (sp1 + sp8);
    out[1] = sim1;
    out[2] = sim8;
    out[3] = sp1;
    out[4] = sp8;
  }
}

// ---------------- launcher ----------------
// ws layout (bytes):
//   0        : double entpart[2][2048]      32768
//   32768    : int    labels[B]             32768
//   65536    : float  msp1[256]             1024
//   66560    : float  msp8[256]             1024
//   69632    : float  w1[B]                 32768
//   102400   : float  diag1[B]              32768
//   135168   : float  w8[B]                 32768
//   167936   : float  diag8[B]              32768
//   200704   : float  Cpart1[16][K][D]      16777216
//   16978944 : float  Cpart8[16][K][D]      16777216
//   total ~34 MB (ws_size observed ~539 MB)

extern "C" void kernel_launch(void* const* d_in, const int* in_sizes, int n_in,
                              void* d_out, int out_size, void* d_ws, size_t ws_size,
                              hipStream_t stream) {
  const float* probs = (const float*)d_in[0];
  const float* a1 = (const float*)d_in[1];
  const float* a8 = (const float*)d_in[2];
  const float* m1 = (const float*)d_in[3];
  const float* m8 = (const float*)d_in[4];
  float* out = (float*)d_out;
  char* ws = (char*)d_ws;

  double* entpart = (double*)(ws + 0);
  int* labels = (int*)(ws + 32768);
  float* msp1 = (float*)(ws + 65536);
  float* msp8 = (float*)(ws + 66560);
  float* w1 = (float*)(ws + 69632);
  float* diag1 = (float*)(ws + 102400);
  float* w8 = (float*)(ws + 135168);
  float* diag8 = (float*)(ws + 167936);
  float* Cpart1 = (float*)(ws + 200704);
  float* Cpart8 = (float*)(ws + 16978944);

  k_labels<<<B_ / 4, 256, 0, stream>>>(probs, labels);
  // per-tensor pairing: scatter re-reads the tensor norms just pulled into L3,
  // both passes fully sequential (no rowlist gather anywhere)
  k_norms<<<B_, 256, 0, stream>>>(a1, w1, diag1);
  k_scatter<<<TILES * RSPLIT, 256, 0, stream>>>(a1, labels, w1, Cpart1);
  k_norms<<<B_, 256, 0, stream>>>(a8, w8, diag8);
  k_scatter<<<TILES * RSPLIT, 256, 0, stream>>>(a8, labels, w8, Cpart8);
  k_entropy<<<ENT_GRID, 256, 0, stream>>>((const f32x4*)m1, (const f32x4*)m8, entpart);
  k_msm<<<512, 256, 0, stream>>>(Cpart1, Cpart8, msp1, msp8);
  k_final<<<1, 256, 0, stream>>>(entpart, labels, diag1, diag8, msp1, msp8, out);
}